// Round 15
// baseline (2621.180 us; speedup 1.0000x reference)
//
#include <hip/hip_runtime.h>

typedef unsigned short U16;
typedef unsigned int   U32;
typedef unsigned long long U64;
typedef __attribute__((ext_vector_type(8))) short S8;
typedef __attribute__((ext_vector_type(4))) float F4;

#define B_  64
#define T_  512
#define DD  768
#define HH  384
#define G4  1536
#define NL  33

__device__ __forceinline__ U16 f2bf(float f){
  U32 u = __float_as_uint(f);
  u += 0x7fffu + ((u >> 16) & 1u);
  return (U16)(u >> 16);
}
__device__ __forceinline__ float bf2f(U16 h){ return __uint_as_float(((U32)h) << 16); }
__device__ __forceinline__ float frcp(float x){
  float r;
  asm("v_rcp_f32 %0, %1" : "=v"(r) : "v"(x));
  return r;
}
__device__ __forceinline__ float sigm(float x){
  return frcp(1.f + __expf(-x));
}
__device__ __forceinline__ float tanh_(float x){
  float e = __expf(2.f * x);
  return 1.f - 2.f * frcp(e + 1.f);
}

// ---------------- fused: lengths + weight casts + x cast ----------------
__global__ void k_pre(const float* x, U64* xb, const U32* mask, int* lens,
                      const float* wf_, const float* wb_, const float* lw_,
                      const float* bfv, const float* bbv,
                      U16* wcat, U16* lwb, float* bcat){
  int blk = blockIdx.x;
  int tid = threadIdx.x;
  if (blk < 64){
    if (tid < 64){
      int b = blk, l = tid;
      bool b32 = (mask[0] == 1u);   // int32 mask: word0==1; bool mask: 0x01010101
      int cnt = 0;
      for (int t = l; t < T_; t += 64){
        int v = b32 ? ((const int*)mask)[b * T_ + t]
                    : (int)((const unsigned char*)mask)[b * T_ + t];
        cnt += (v != 0);
      }
      #pragma unroll
      for (int o = 32; o >= 1; o >>= 1) cnt += __shfl_xor(cnt, o);
      if (l == 0) lens[b] = cnt;
    }
    return;
  }
  if (blk < 1088){
    const int WE = G4 * DD;
    const int LWE = NL * DD;
    int total = 2 * WE + LWE + 2 * G4;
    for (int i = (blk - 64) * 256 + tid; i < total; i += 1024 * 256){
      if (i < WE) wcat[i] = f2bf(wf_[i]);
      else if (i < 2 * WE) wcat[i] = f2bf(wb_[i - WE]);
      else if (i < 2 * WE + LWE) lwb[i - 2 * WE] = f2bf(lw_[i - 2 * WE]);
      else { int j = i - 2 * WE - LWE; bcat[j] = (j < G4) ? bfv[j] : bbv[j - G4]; }
    }
    return;
  }
  size_t n4 = (size_t)B_ * T_ * DD / 4;
  for (size_t i = (size_t)(blk - 1088) * 256 + tid; i < n4; i += (size_t)2048 * 256){
    float4 v = ((const float4*)x)[i];
    U64 o = (U64)f2bf(v.x) | ((U64)f2bf(v.y) << 16) | ((U64)f2bf(v.z) << 32) | ((U64)f2bf(v.w) << 48);
    xb[i] = o;
  }
}

// ---------------- xp GEMM: 256x256 tile, BK=64, 2-phase double-buffered LDS ----------
// (r14-proven) per K-step { STAGE(next -> alt buf, async); COMPUTE(cur); barrier }.
// 512 threads = 8 waves (2M x 4N). Swizzle: pre-swizzled global source + linear
// gload_lds dest + XOR frag read. XCD swizzle: 1536 = 8 x 192 bijective.
__global__ __launch_bounds__(512, 1) void k_gemm(const U16* __restrict__ A,
                                                 const U16* __restrict__ Bw,
                                                 const float* __restrict__ bias, U16* C){
  __shared__ __align__(16) U16 lds[4][256 * 64];   // As0|Bs0|As1|Bs1 = 128 KiB
  int swz = (blockIdx.x & 7) * 192 + (blockIdx.x >> 3);   // 1536 = 8*192, bijective
  int mb = swz & 127, nb = swz >> 7;                      // nb 0..11
  int m0 = mb * 256, n0 = nb * 256;
  int tid = threadIdx.x;
  int w = tid >> 6, l = tid & 63;
  int lr = l & 15, lk = (l >> 4) * 8;
  int wr = (w >> 2) * 128, wc = (w & 3) * 64;   // wave quadrant
  int srow = tid >> 3;                          // 0..63
  int scol = (tid & 7) * 8;

  float bv[4];
  #pragma unroll
  for (int j = 0; j < 4; j++) bv[j] = bias[n0 + wc + j * 16 + lr];

  F4 acc[8][4];
  #pragma unroll
  for (int i = 0; i < 8; i++)
    #pragma unroll
    for (int j = 0; j < 4; j++) acc[i][j] = (F4){0.f, 0.f, 0.f, 0.f};

  #define STAGE(BUF, KT) { \
    _Pragma("unroll") \
    for (int rr = 0; rr < 4; rr++){ \
      int row = rr * 64 + srow; \
      int sw = scol ^ ((row & 7) * 8); \
      __builtin_amdgcn_global_load_lds((const U32*)(A + (size_t)(m0 + row) * DD + (KT) + sw), \
                                       (U32*)(&lds[(BUF) * 2][row * 64 + scol]), 16, 0, 0); \
      __builtin_amdgcn_global_load_lds((const U32*)(Bw + (size_t)(n0 + row) * DD + (KT) + sw), \
                                       (U32*)(&lds[(BUF) * 2 + 1][row * 64 + scol]), 16, 0, 0); \
    } }

  #define COMPUTE(BUF) { \
    _Pragma("unroll") \
    for (int kk = 0; kk < 64; kk += 32){ \
      int cs = (kk + lk) ^ ((lr & 7) * 8); \
      S8 af[8], bf[4]; \
      _Pragma("unroll") \
      for (int i = 0; i < 8; i++) af[i] = *(const S8*)(&lds[(BUF) * 2][(wr + i * 16 + lr) * 64 + cs]); \
      _Pragma("unroll") \
      for (int j = 0; j < 4; j++) bf[j] = *(const S8*)(&lds[(BUF) * 2 + 1][(wc + j * 16 + lr) * 64 + cs]); \
      _Pragma("unroll") \
      for (int i = 0; i < 8; i++) \
        _Pragma("unroll") \
        for (int j = 0; j < 4; j++) \
          acc[i][j] = __builtin_amdgcn_mfma_f32_16x16x32_bf16(af[i], bf[j], acc[i][j], 0, 0, 0); \
    } }

  STAGE(0, 0)
  __syncthreads();
  int cur = 0;
  for (int t = 1; t < 12; ++t){
    STAGE(cur ^ 1, t * 64)
    COMPUTE(cur)
    __syncthreads();
    cur ^= 1;
  }
  COMPUTE(cur)

  #pragma unroll
  for (int j = 0; j < 4; j++){
    int col = n0 + wc + j * 16 + lr;
    #pragma unroll
    for (int i = 0; i < 8; i++){
      #pragma unroll
      for (int rg = 0; rg < 4; rg++){
        int row = m0 + wr + i * 16 + (l >> 4) * 4 + rg;
        C[(size_t)row * 3072 + col] = f2bf(acc[i][j][rg] + bv[j]);
      }
    }
  }
  #undef STAGE
  #undef COMPUTE
}

// ---------------- LSTM recurrence: 3-member groups (straggler-arity cut) --------------
// 24 blocks = 8 groups (4 seq-chunks x 2 dirs) x 3 members x 512 threads (8 waves,
// 2 waves/SIMD at 256 VGPR). Member m owns j in [m*128, m*128+128). Protocol and hx
// layout byte-identical to r12/r3: word (U64) = [tag:32 | row(2p+1) bf16 | row(2p)
// bf16], idx = j*8+p, per (parity,group) 3072 words; publish step s -> tag s+1 parity
// (s+1)&1; consume at s polls tag==s; inductive poll-all gate. THEORY (r14 post-mortem):
// cycle = max over MEMBERS' publish + ~700cyc retry quantization; halving member count
// (6->3) cuts the straggler max and halves signal traffic; per-thread poll 12 -> 6 words.
__global__ __launch_bounds__(512, 1) void k_rec(const U16* __restrict__ xp,
                                                const float* __restrict__ whf,
                                                const float* __restrict__ whb,
                                                const int* __restrict__ len_,
                                                U16* __restrict__ hcat, U64* hx){
  int blk = blockIdx.x;
  int g = blk & 7, m = blk >> 3;          // g: group, m: member 0..2
  int dir = g >> 2, chunk = g & 3, sb = chunk * 16;
  const float* wh = dir ? whb : whf;
  int tid = threadIdx.x;
  int w = tid >> 6, l = tid & 63;         // w 0..7
  int lr = l & 15, lq = l >> 4;
  int jloc = m * 128 + w * 16 + lr;       // j in [0,384)

  S8 wf[4][12];
  #pragma unroll
  for (int q = 0; q < 4; q++){
    #pragma unroll
    for (int kc = 0; kc < 12; kc++){
      const float* p = wh + (size_t)(q * HH + jloc) * HH + kc * 32 + lq * 8;
      float4 v0 = *(const float4*)p;
      float4 v1 = *(const float4*)(p + 4);
      S8 t;
      t[0] = (short)f2bf(v0.x); t[1] = (short)f2bf(v0.y); t[2] = (short)f2bf(v0.z); t[3] = (short)f2bf(v0.w);
      t[4] = (short)f2bf(v1.x); t[5] = (short)f2bf(v1.y); t[6] = (short)f2bf(v1.z); t[7] = (short)f2bf(v1.w);
      wf[q][kc] = t;
    }
  }

  __shared__ __align__(16) U16 hl[16][408];   // h[seq][hdim], padded stride
  for (int i = tid; i < 16 * 408; i += 512) ((U16*)hl)[i] = 0;
  int lens[4];
  #pragma unroll
  for (int r = 0; r < 4; r++) lens[r] = len_[sb + lq * 4 + r];
  int steps = len_[sb];                        // lengths sorted desc -> group max
  float cst[4] = {0.f, 0.f, 0.f, 0.f}, hst[4] = {0.f, 0.f, 0.f, 0.f};
  __syncthreads();

  for (int step = 0; step < steps; ++step){
    // xp prefetch: issued before the poll (HBM latency hides under the wait)
    float xv[4][4];
    #pragma unroll
    for (int r = 0; r < 4; r++){
      int L = lens[r];
      int t = dir ? (L - 1 - step) : step;
      if (t < 0) t = 0;
      size_t basei = ((size_t)(sb + lq * 4 + r) * T_ + t) * 3072 + dir * G4;
      #pragma unroll
      for (int q = 0; q < 4; q++) xv[q][r] = bf2f(xp[basei + q * HH + jloc]);
    }
    if (step){
      const U64* src = hx + (size_t)((step & 1) * 8 + g) * 3072;
      U64 v[6];
      #pragma unroll
      for (int k = 0; k < 6; k++)
        v[k] = __hip_atomic_load(src + tid + k * 512, __ATOMIC_RELAXED, __HIP_MEMORY_SCOPE_AGENT);
      U32 expct = (U32)step;
      while (true){
        U32 bad = 0;
        #pragma unroll
        for (int k = 0; k < 6; k++) bad |= (((U32)(v[k] >> 32)) != expct) ? (1u << k) : 0u;
        if (!bad) break;
        #pragma unroll
        for (int k = 0; k < 6; k++)
          if (bad & (1u << k))
            v[k] = __hip_atomic_load(src + tid + k * 512, __ATOMIC_RELAXED, __HIP_MEMORY_SCOPE_AGENT);
      }
      #pragma unroll
      for (int k = 0; k < 6; k++){
        int wi = tid + k * 512;
        int col = wi >> 3, p = wi & 7;
        U32 lo = (U32)v[k];
        hl[2 * p + 0][col] = (U16)lo;
        hl[2 * p + 1][col] = (U16)(lo >> 16);
      }
      // LDS-only drain + barrier (do NOT drain vmcnt: publish/hcat stores of the
      // previous iteration and this step's xp loads may stay in flight)
      asm volatile("s_waitcnt lgkmcnt(0)" ::: "memory");
      __builtin_amdgcn_s_barrier();
      asm volatile("" ::: "memory");
      __builtin_amdgcn_sched_barrier(0);
    }
    // g = h @ Wslice^T
    F4 acc[4];
    #pragma unroll
    for (int q = 0; q < 4; q++) acc[q] = (F4){0.f, 0.f, 0.f, 0.f};
    #pragma unroll
    for (int kc = 0; kc < 12; kc++){
      S8 a = *(const S8*)&hl[lr][kc * 32 + lq * 8];
      #pragma unroll
      for (int q = 0; q < 4; q++)
        acc[q] = __builtin_amdgcn_mfma_f32_16x16x32_bf16(a, wf[q][kc], acc[q], 0, 0, 0);
    }
    // activations (quadruples lane-local: seq=(l>>4)*4+reg, j=l&15)
    #pragma unroll
    for (int r = 0; r < 4; r++){
      float ip = acc[0][r] + xv[0][r];
      float fp = acc[1][r] + xv[1][r];
      float gp = acc[2][r] + xv[2][r];
      float op = acc[3][r] + xv[3][r];
      float cn = sigm(fp) * cst[r] + sigm(ip) * tanh_(gp);
      float hn = sigm(op) * tanh_(cn);
      if (step < lens[r]){ cst[r] = cn; hst[r] = hn; }
    }
    // publish FIRST (critical path), hcat after
    {
      U64 tag = ((U64)(U32)(step + 1)) << 32;
      U64 w0 = (U64)((U32)f2bf(hst[0]) | ((U32)f2bf(hst[1]) << 16)) | tag;
      U64 w1 = (U64)((U32)f2bf(hst[2]) | ((U32)f2bf(hst[3]) << 16)) | tag;
      U64* dst = hx + (size_t)(((step + 1) & 1) * 8 + g) * 3072 + jloc * 8 + lq * 2;
      __hip_atomic_store(dst + 0, w0, __ATOMIC_RELAXED, __HIP_MEMORY_SCOPE_AGENT);
      __hip_atomic_store(dst + 1, w1, __ATOMIC_RELAXED, __HIP_MEMORY_SCOPE_AGENT);
    }
    #pragma unroll
    for (int r = 0; r < 4; r++){
      if (step < lens[r]){
        int t = dir ? (lens[r] - 1 - step) : step;
        hcat[((size_t)(sb + lq * 4 + r) * T_ + t) * (2 * HH) + dir * HH + jloc] = f2bf(hst[r]);
      }
    }
  }
}

// ---------------- emissions: em = h @ lin_w^T + lin_b (32 rows/block) ----------------
__global__ __launch_bounds__(256) void k_em(const U16* hcat, const U16* lwb, const float* lin_b, float* em){
  __shared__ __align__(16) U16 lw[NL * DD];
  __shared__ __align__(16) U16 hs[32 * DD];
  int tid = threadIdx.x;
  for (int i = tid; i < NL * DD / 4; i += 256) ((U64*)lw)[i] = ((const U64*)lwb)[i];
  size_t r0 = (size_t)blockIdx.x * 32;
  const U64* hsrc = (const U64*)(hcat + r0 * DD);
  for (int i = tid; i < 32 * DD / 4; i += 256) ((U64*)hs)[i] = hsrc[i];
  __syncthreads();
  for (int e = tid; e < 32 * NL; e += 256){
    int rr = e / NL, ll = e % NL;
    const U16* hp = &hs[rr * DD];
    const U16* wp = &lw[ll * DD];
    float s = 0.f;
    #pragma unroll 8
    for (int k = 0; k < DD; k += 2){
      U32 hv = *(const U32*)&hp[k];
      U32 wv = *(const U32*)&wp[k];
      s = fmaf(__uint_as_float(hv << 16), __uint_as_float(wv << 16), s);
      s = fmaf(__uint_as_float(hv & 0xffff0000u), __uint_as_float(wv & 0xffff0000u), s);
    }
    em[(r0 + rr) * NL + ll] = s + lin_b[ll];
  }
}

// ---------------- CRF: single-wave, shuffle-broadcast alpha recursion ----------------
__global__ void k_crf(const float* em, const int* labels, const int* len_, const float* trans,
                      const float* startt, const float* endt, float* score){
  int b = blockIdx.x, l = threadIdx.x;
  int L = len_[b];
  const int* lab = labels + b * T_;
  const float* emb = em + (size_t)b * T_ * NL;
  float part = 0.f;
  for (int t = 1 + l; t < L; t += 64){
    int lp = lab[t - 1], lc = lab[t];
    part += trans[lp * NL + lc] + emb[(size_t)t * NL + lc];
  }
  #pragma unroll
  for (int o = 32; o >= 1; o >>= 1) part += __shfl_xor(part, o);
  float num = part + startt[lab[0]] + emb[lab[0]] + endt[lab[L - 1]];
  bool act = l < NL;
  int jj = act ? l : (NL - 1);
  float tc[NL];
  #pragma unroll
  for (int i = 0; i < NL; i++) tc[i] = trans[i * NL + jj];
  float a = startt[jj] + emb[jj];
  for (int t = 1; t < L; ++t){
    float vv[NL];
    float mx = -3.0e38f;
    #pragma unroll
    for (int i = 0; i < NL; i++){ vv[i] = __shfl(a, i) + tc[i]; mx = fmaxf(mx, vv[i]); }
    float s = 0.f;
    #pragma unroll
    for (int i = 0; i < NL; i++) s += __expf(vv[i] - mx);
    a = mx + __logf(s) + emb[(size_t)t * NL + jj];
  }
  float val = act ? (a + endt[jj]) : -3.0e38f;
  float mx = val;
  #pragma unroll
  for (int o = 32; o >= 1; o >>= 1) mx = fmaxf(mx, __shfl_xor(mx, o));
  float se = __expf(val - mx);
  #pragma unroll
  for (int o = 32; o >= 1; o >>= 1) se += __shfl_xor(se, o);
  float logZ = mx + __logf(se);
  if (l == 0) score[b] = num - logZ;
}

__global__ void k_final(const float* score, float* out){
  int l = threadIdx.x;
  float v = score[l];
  #pragma unroll
  for (int o = 32; o >= 1; o >>= 1) v += __shfl_xor(v, o);
  if (l == 0) out[0] = -v / 64.f;
}

__global__ void k_sentinel(float* out){ out[0] = -12345.f; }

extern "C" void kernel_launch(void* const* d_in, const int* in_sizes, int n_in,
                              void* d_out, int out_size, void* d_ws, size_t ws_size,
                              hipStream_t stream){
  const float* x      = (const float*)d_in[0];
  const void*  mask   = d_in[1];
  const int*   labels = (const int*)d_in[2];
  const float* w_ih_f = (const float*)d_in[4];
  const float* w_hh_f = (const float*)d_in[5];
  const float* b_f    = (const float*)d_in[6];
  const float* w_ih_b = (const float*)d_in[7];
  const float* w_hh_b = (const float*)d_in[8];
  const float* b_b    = (const float*)d_in[9];
  const float* lin_w  = (const float*)d_in[10];
  const float* lin_b  = (const float*)d_in[11];
  const float* trans  = (const float*)d_in[12];
  const float* startt = (const float*)d_in[13];
  const float* endt   = (const float*)d_in[14];
  float* out = (float*)d_out;

  const size_t WS_NEEDED = 261158912;
  if (ws_size < WS_NEEDED){
    k_sentinel<<<1, 1, 0, stream>>>(out);
    return;
  }

  char* ws = (char*)d_ws;
  size_t off = 0;
  auto take = [&](size_t bytes) -> char* {
    char* p = ws + off;
    off += (bytes + 255) & ~(size_t)255;
    return p;
  };
  U16*  xp    = (U16*)take((size_t)32768 * 3072 * 2);   // 201.3 MB
  U16*  hcat  = (U16*)take((size_t)32768 * 768 * 2);    // 50.3 MB (doubles as x_bf16)
  U16*  wcat  = (U16*)take((size_t)3072 * 768 * 2);
  U16*  lwb   = (U16*)take((size_t)NL * 768 * 2);
  float* bcat = (float*)take(3072 * 4);
  int*  lens  = (int*)take(256);
  U64*  hx    = (U64*)take((size_t)2 * 8 * 3072 * 8);   // 384 KB tagged exchange
  float* em   = (float*)take((size_t)32768 * NL * 4);
  float* score= (float*)take(256);
  U16*  xbf   = hcat;   // alias: x_bf16 lives here until GEMM done, then region becomes h_cat

  (void)hipMemsetAsync(hx, 0, (size_t)2 * 8 * 3072 * 8, stream);  // clear tags (replay safety)
  k_pre<<<3136, 256, 0, stream>>>(x, (U64*)xbf, (const U32*)mask, lens,
                                  w_ih_f, w_ih_b, lin_w, b_f, b_b, wcat, lwb, bcat);
  k_gemm<<<1536, 512, 0, stream>>>(xbf, wcat, bcat, xp);
  k_rec<<<24, 512, 0, stream>>>(xp, w_hh_f, w_hh_b, lens, hcat, hx);
  k_em<<<1024, 256, 0, stream>>>(hcat, lwb, lin_b, em);
  k_crf<<<64, 64, 0, stream>>>(em, labels, lens, trans, startt, endt, score);
  k_final<<<1, 64, 0, stream>>>(score, out);
}

// Round 16
// 2057.595 us; speedup vs baseline: 1.2739x; 1.2739x over previous
//
#include <hip/hip_runtime.h>

typedef unsigned short U16;
typedef unsigned int   U32;
typedef unsigned long long U64;
typedef __attribute__((ext_vector_type(8))) short S8;
typedef __attribute__((ext_vector_type(4))) float F4;

#define B_  64
#define T_  512
#define DD  768
#define HH  384
#define G4  1536
#define NL  33

__device__ __forceinline__ U16 f2bf(float f){
  U32 u = __float_as_uint(f);
  u += 0x7fffu + ((u >> 16) & 1u);
  return (U16)(u >> 16);
}
__device__ __forceinline__ float bf2f(U16 h){ return __uint_as_float(((U32)h) << 16); }
__device__ __forceinline__ float frcp(float x){
  float r;
  asm("v_rcp_f32 %0, %1" : "=v"(r) : "v"(x));
  return r;
}
__device__ __forceinline__ float sigm(float x){
  return frcp(1.f + __expf(-x));
}
__device__ __forceinline__ float tanh_(float x){
  float e = __expf(2.f * x);
  return 1.f - 2.f * frcp(e + 1.f);
}

// ---------------- fused: lengths + weight casts + x cast ----------------
__global__ void k_pre(const float* x, U64* xb, const U32* mask, int* lens,
                      const float* wf_, const float* wb_, const float* lw_,
                      const float* bfv, const float* bbv,
                      U16* wcat, U16* lwb, float* bcat){
  int blk = blockIdx.x;
  int tid = threadIdx.x;
  if (blk < 64){
    if (tid < 64){
      int b = blk, l = tid;
      bool b32 = (mask[0] == 1u);   // int32 mask: word0==1; bool mask: 0x01010101
      int cnt = 0;
      for (int t = l; t < T_; t += 64){
        int v = b32 ? ((const int*)mask)[b * T_ + t]
                    : (int)((const unsigned char*)mask)[b * T_ + t];
        cnt += (v != 0);
      }
      #pragma unroll
      for (int o = 32; o >= 1; o >>= 1) cnt += __shfl_xor(cnt, o);
      if (l == 0) lens[b] = cnt;
    }
    return;
  }
  if (blk < 1088){
    const int WE = G4 * DD;
    const int LWE = NL * DD;
    int total = 2 * WE + LWE + 2 * G4;
    for (int i = (blk - 64) * 256 + tid; i < total; i += 1024 * 256){
      if (i < WE) wcat[i] = f2bf(wf_[i]);
      else if (i < 2 * WE) wcat[i] = f2bf(wb_[i - WE]);
      else if (i < 2 * WE + LWE) lwb[i - 2 * WE] = f2bf(lw_[i - 2 * WE]);
      else { int j = i - 2 * WE - LWE; bcat[j] = (j < G4) ? bfv[j] : bbv[j - G4]; }
    }
    return;
  }
  size_t n4 = (size_t)B_ * T_ * DD / 4;
  for (size_t i = (size_t)(blk - 1088) * 256 + tid; i < n4; i += (size_t)2048 * 256){
    float4 v = ((const float4*)x)[i];
    U64 o = (U64)f2bf(v.x) | ((U64)f2bf(v.y) << 16) | ((U64)f2bf(v.z) << 32) | ((U64)f2bf(v.w) << 48);
    xb[i] = o;
  }
}

// ---------------- xp GEMM: 256x256 tile, BK=64, 2-phase double-buffered LDS ----------
// (r14-proven) per K-step { STAGE(next -> alt buf, async); COMPUTE(cur); barrier }.
// 512 threads = 8 waves (2M x 4N). Swizzle: pre-swizzled global source + linear
// gload_lds dest + XOR frag read. XCD swizzle: 1536 = 8 x 192 bijective.
__global__ __launch_bounds__(512, 1) void k_gemm(const U16* __restrict__ A,
                                                 const U16* __restrict__ Bw,
                                                 const float* __restrict__ bias, U16* C){
  __shared__ __align__(16) U16 lds[4][256 * 64];   // As0|Bs0|As1|Bs1 = 128 KiB
  int swz = (blockIdx.x & 7) * 192 + (blockIdx.x >> 3);   // 1536 = 8*192, bijective
  int mb = swz & 127, nb = swz >> 7;                      // nb 0..11
  int m0 = mb * 256, n0 = nb * 256;
  int tid = threadIdx.x;
  int w = tid >> 6, l = tid & 63;
  int lr = l & 15, lk = (l >> 4) * 8;
  int wr = (w >> 2) * 128, wc = (w & 3) * 64;   // wave quadrant
  int srow = tid >> 3;                          // 0..63
  int scol = (tid & 7) * 8;

  float bv[4];
  #pragma unroll
  for (int j = 0; j < 4; j++) bv[j] = bias[n0 + wc + j * 16 + lr];

  F4 acc[8][4];
  #pragma unroll
  for (int i = 0; i < 8; i++)
    #pragma unroll
    for (int j = 0; j < 4; j++) acc[i][j] = (F4){0.f, 0.f, 0.f, 0.f};

  #define STAGE(BUF, KT) { \
    _Pragma("unroll") \
    for (int rr = 0; rr < 4; rr++){ \
      int row = rr * 64 + srow; \
      int sw = scol ^ ((row & 7) * 8); \
      __builtin_amdgcn_global_load_lds((const U32*)(A + (size_t)(m0 + row) * DD + (KT) + sw), \
                                       (U32*)(&lds[(BUF) * 2][row * 64 + scol]), 16, 0, 0); \
      __builtin_amdgcn_global_load_lds((const U32*)(Bw + (size_t)(n0 + row) * DD + (KT) + sw), \
                                       (U32*)(&lds[(BUF) * 2 + 1][row * 64 + scol]), 16, 0, 0); \
    } }

  #define COMPUTE(BUF) { \
    _Pragma("unroll") \
    for (int kk = 0; kk < 64; kk += 32){ \
      int cs = (kk + lk) ^ ((lr & 7) * 8); \
      S8 af[8], bf[4]; \
      _Pragma("unroll") \
      for (int i = 0; i < 8; i++) af[i] = *(const S8*)(&lds[(BUF) * 2][(wr + i * 16 + lr) * 64 + cs]); \
      _Pragma("unroll") \
      for (int j = 0; j < 4; j++) bf[j] = *(const S8*)(&lds[(BUF) * 2 + 1][(wc + j * 16 + lr) * 64 + cs]); \
      _Pragma("unroll") \
      for (int i = 0; i < 8; i++) \
        _Pragma("unroll") \
        for (int j = 0; j < 4; j++) \
          acc[i][j] = __builtin_amdgcn_mfma_f32_16x16x32_bf16(af[i], bf[j], acc[i][j], 0, 0, 0); \
    } }

  STAGE(0, 0)
  __syncthreads();
  int cur = 0;
  for (int t = 1; t < 12; ++t){
    STAGE(cur ^ 1, t * 64)
    COMPUTE(cur)
    __syncthreads();
    cur ^= 1;
  }
  COMPUTE(cur)

  #pragma unroll
  for (int j = 0; j < 4; j++){
    int col = n0 + wc + j * 16 + lr;
    #pragma unroll
    for (int i = 0; i < 8; i++){
      #pragma unroll
      for (int rg = 0; rg < 4; rg++){
        int row = m0 + wr + i * 16 + (l >> 4) * 4 + rg;
        C[(size_t)row * 3072 + col] = f2bf(acc[i][j][rg] + bv[j]);
      }
    }
  }
  #undef STAGE
  #undef COMPUTE
}

// ---------------- LSTM recurrence: r12/r14-proven (r3 protocol + LDS-only barrier) ----
// 48 blocks = 8 groups (4 seq-chunks x 2 dirs) x 6 members x 256 threads (1 wave/SIMD,
// 256 VGPR headroom -- r15 showed 512-thr/3-member halves the VGPR budget and regresses).
// hx word (U64) = [tag:32 | row(2p+1) bf16 | row(2p) bf16], idx = j*8+p, per
// (parity,group) 3072 words. Publish step s -> tag s+1, parity (s+1)&1; consumer at
// step s polls parity s&1 for tag==s. Overwrite-safety: inductive poll-all gate (r3).
__global__ __launch_bounds__(256, 1) void k_rec(const U16* __restrict__ xp,
                                                const float* __restrict__ whf,
                                                const float* __restrict__ whb,
                                                const int* __restrict__ len_,
                                                U16* __restrict__ hcat, U64* hx){
  int blk = blockIdx.x;
  int g = blk & 7, m = blk >> 3;
  int dir = g >> 2, chunk = g & 3, sb = chunk * 16;
  const float* wh = dir ? whb : whf;
  int tid = threadIdx.x;
  int w = tid >> 6, l = tid & 63;
  int lr = l & 15, lq = l >> 4;
  int jloc = m * 64 + w * 16 + lr;        // j in [0,384)

  S8 wf[4][12];
  #pragma unroll
  for (int q = 0; q < 4; q++){
    #pragma unroll
    for (int kc = 0; kc < 12; kc++){
      const float* p = wh + (size_t)(q * HH + jloc) * HH + kc * 32 + lq * 8;
      float4 v0 = *(const float4*)p;
      float4 v1 = *(const float4*)(p + 4);
      S8 t;
      t[0] = (short)f2bf(v0.x); t[1] = (short)f2bf(v0.y); t[2] = (short)f2bf(v0.z); t[3] = (short)f2bf(v0.w);
      t[4] = (short)f2bf(v1.x); t[5] = (short)f2bf(v1.y); t[6] = (short)f2bf(v1.z); t[7] = (short)f2bf(v1.w);
      wf[q][kc] = t;
    }
  }

  __shared__ __align__(16) U16 hl[16][408];   // h[seq][hdim], padded stride
  for (int i = tid; i < 16 * 408; i += 256) ((U16*)hl)[i] = 0;
  int lens[4];
  #pragma unroll
  for (int r = 0; r < 4; r++) lens[r] = len_[sb + lq * 4 + r];
  int steps = len_[sb];                        // lengths sorted desc -> group max
  float cst[4] = {0.f, 0.f, 0.f, 0.f}, hst[4] = {0.f, 0.f, 0.f, 0.f};
  __syncthreads();

  for (int step = 0; step < steps; ++step){
    // xp prefetch: issued before the poll (HBM latency hides under the wait)
    float xv[4][4];
    #pragma unroll
    for (int r = 0; r < 4; r++){
      int L = lens[r];
      int t = dir ? (L - 1 - step) : step;
      if (t < 0) t = 0;
      size_t basei = ((size_t)(sb + lq * 4 + r) * T_ + t) * 3072 + dir * G4;
      #pragma unroll
      for (int q = 0; q < 4; q++) xv[q][r] = bf2f(xp[basei + q * HH + jloc]);
    }
    if (step){
      const U64* src = hx + (size_t)((step & 1) * 8 + g) * 3072;
      U64 v[12];
      #pragma unroll
      for (int k = 0; k < 12; k++)
        v[k] = __hip_atomic_load(src + tid + k * 256, __ATOMIC_RELAXED, __HIP_MEMORY_SCOPE_AGENT);
      U32 expct = (U32)step;
      while (true){
        U32 bad = 0;
        #pragma unroll
        for (int k = 0; k < 12; k++) bad |= (((U32)(v[k] >> 32)) != expct) ? (1u << k) : 0u;
        if (!bad) break;
        #pragma unroll
        for (int k = 0; k < 12; k++)
          if (bad & (1u << k))
            v[k] = __hip_atomic_load(src + tid + k * 256, __ATOMIC_RELAXED, __HIP_MEMORY_SCOPE_AGENT);
      }
      #pragma unroll
      for (int k = 0; k < 12; k++){
        int wi = tid + k * 256;
        int col = wi >> 3, p = wi & 7;
        U32 lo = (U32)v[k];
        hl[2 * p + 0][col] = (U16)lo;
        hl[2 * p + 1][col] = (U16)(lo >> 16);
      }
      // LDS-only drain + barrier (do NOT drain vmcnt: publish/hcat stores of the
      // previous iteration and this step's xp loads may stay in flight)
      asm volatile("s_waitcnt lgkmcnt(0)" ::: "memory");
      __builtin_amdgcn_s_barrier();
      asm volatile("" ::: "memory");
      __builtin_amdgcn_sched_barrier(0);
    }
    // g = h @ Wslice^T
    F4 acc[4];
    #pragma unroll
    for (int q = 0; q < 4; q++) acc[q] = (F4){0.f, 0.f, 0.f, 0.f};
    #pragma unroll
    for (int kc = 0; kc < 12; kc++){
      S8 a = *(const S8*)&hl[lr][kc * 32 + lq * 8];
      #pragma unroll
      for (int q = 0; q < 4; q++)
        acc[q] = __builtin_amdgcn_mfma_f32_16x16x32_bf16(a, wf[q][kc], acc[q], 0, 0, 0);
    }
    // activations (quadruples lane-local: seq=(l>>4)*4+reg, j=l&15)
    #pragma unroll
    for (int r = 0; r < 4; r++){
      float ip = acc[0][r] + xv[0][r];
      float fp = acc[1][r] + xv[1][r];
      float gp = acc[2][r] + xv[2][r];
      float op = acc[3][r] + xv[3][r];
      float cn = sigm(fp) * cst[r] + sigm(ip) * tanh_(gp);
      float hn = sigm(op) * tanh_(cn);
      if (step < lens[r]){ cst[r] = cn; hst[r] = hn; }
    }
    // publish FIRST (critical path), hcat after
    {
      U64 tag = ((U64)(U32)(step + 1)) << 32;
      U64 w0 = (U64)((U32)f2bf(hst[0]) | ((U32)f2bf(hst[1]) << 16)) | tag;
      U64 w1 = (U64)((U32)f2bf(hst[2]) | ((U32)f2bf(hst[3]) << 16)) | tag;
      U64* dst = hx + (size_t)(((step + 1) & 1) * 8 + g) * 3072 + jloc * 8 + lq * 2;
      __hip_atomic_store(dst + 0, w0, __ATOMIC_RELAXED, __HIP_MEMORY_SCOPE_AGENT);
      __hip_atomic_store(dst + 1, w1, __ATOMIC_RELAXED, __HIP_MEMORY_SCOPE_AGENT);
    }
    #pragma unroll
    for (int r = 0; r < 4; r++){
      if (step < lens[r]){
        int t = dir ? (lens[r] - 1 - step) : step;
        hcat[((size_t)(sb + lq * 4 + r) * T_ + t) * (2 * HH) + dir * HH + jloc] = f2bf(hst[r]);
      }
    }
  }
}

// ---------------- emissions: em = h @ lin_w^T + lin_b (32 rows/block) ----------------
__global__ __launch_bounds__(256) void k_em(const U16* hcat, const U16* lwb, const float* lin_b, float* em){
  __shared__ __align__(16) U16 lw[NL * DD];
  __shared__ __align__(16) U16 hs[32 * DD];
  int tid = threadIdx.x;
  for (int i = tid; i < NL * DD / 4; i += 256) ((U64*)lw)[i] = ((const U64*)lwb)[i];
  size_t r0 = (size_t)blockIdx.x * 32;
  const U64* hsrc = (const U64*)(hcat + r0 * DD);
  for (int i = tid; i < 32 * DD / 4; i += 256) ((U64*)hs)[i] = hsrc[i];
  __syncthreads();
  for (int e = tid; e < 32 * NL; e += 256){
    int rr = e / NL, ll = e % NL;
    const U16* hp = &hs[rr * DD];
    const U16* wp = &lw[ll * DD];
    float s = 0.f;
    #pragma unroll 8
    for (int k = 0; k < DD; k += 2){
      U32 hv = *(const U32*)&hp[k];
      U32 wv = *(const U32*)&wp[k];
      s = fmaf(__uint_as_float(hv << 16), __uint_as_float(wv << 16), s);
      s = fmaf(__uint_as_float(hv & 0xffff0000u), __uint_as_float(wv & 0xffff0000u), s);
    }
    em[(r0 + rr) * NL + ll] = s + lin_b[ll];
  }
}

// ---------------- CRF: single-wave, shuffle-broadcast alpha recursion ----------------
__global__ void k_crf(const float* em, const int* labels, const int* len_, const float* trans,
                      const float* startt, const float* endt, float* score){
  int b = blockIdx.x, l = threadIdx.x;
  int L = len_[b];
  const int* lab = labels + b * T_;
  const float* emb = em + (size_t)b * T_ * NL;
  float part = 0.f;
  for (int t = 1 + l; t < L; t += 64){
    int lp = lab[t - 1], lc = lab[t];
    part += trans[lp * NL + lc] + emb[(size_t)t * NL + lc];
  }
  #pragma unroll
  for (int o = 32; o >= 1; o >>= 1) part += __shfl_xor(part, o);
  float num = part + startt[lab[0]] + emb[lab[0]] + endt[lab[L - 1]];
  bool act = l < NL;
  int jj = act ? l : (NL - 1);
  float tc[NL];
  #pragma unroll
  for (int i = 0; i < NL; i++) tc[i] = trans[i * NL + jj];
  float a = startt[jj] + emb[jj];
  for (int t = 1; t < L; ++t){
    float vv[NL];
    float mx = -3.0e38f;
    #pragma unroll
    for (int i = 0; i < NL; i++){ vv[i] = __shfl(a, i) + tc[i]; mx = fmaxf(mx, vv[i]); }
    float s = 0.f;
    #pragma unroll
    for (int i = 0; i < NL; i++) s += __expf(vv[i] - mx);
    a = mx + __logf(s) + emb[(size_t)t * NL + jj];
  }
  float val = act ? (a + endt[jj]) : -3.0e38f;
  float mx = val;
  #pragma unroll
  for (int o = 32; o >= 1; o >>= 1) mx = fmaxf(mx, __shfl_xor(mx, o));
  float se = __expf(val - mx);
  #pragma unroll
  for (int o = 32; o >= 1; o >>= 1) se += __shfl_xor(se, o);
  float logZ = mx + __logf(se);
  if (l == 0) score[b] = num - logZ;
}

__global__ void k_final(const float* score, float* out){
  int l = threadIdx.x;
  float v = score[l];
  #pragma unroll
  for (int o = 32; o >= 1; o >>= 1) v += __shfl_xor(v, o);
  if (l == 0) out[0] = -v / 64.f;
}

__global__ void k_sentinel(float* out){ out[0] = -12345.f; }

extern "C" void kernel_launch(void* const* d_in, const int* in_sizes, int n_in,
                              void* d_out, int out_size, void* d_ws, size_t ws_size,
                              hipStream_t stream){
  const float* x      = (const float*)d_in[0];
  const void*  mask   = d_in[1];
  const int*   labels = (const int*)d_in[2];
  const float* w_ih_f = (const float*)d_in[4];
  const float* w_hh_f = (const float*)d_in[5];
  const float* b_f    = (const float*)d_in[6];
  const float* w_ih_b = (const float*)d_in[7];
  const float* w_hh_b = (const float*)d_in[8];
  const float* b_b    = (const float*)d_in[9];
  const float* lin_w  = (const float*)d_in[10];
  const float* lin_b  = (const float*)d_in[11];
  const float* trans  = (const float*)d_in[12];
  const float* startt = (const float*)d_in[13];
  const float* endt   = (const float*)d_in[14];
  float* out = (float*)d_out;

  const size_t WS_NEEDED = 261158912;
  if (ws_size < WS_NEEDED){
    k_sentinel<<<1, 1, 0, stream>>>(out);
    return;
  }

  char* ws = (char*)d_ws;
  size_t off = 0;
  auto take = [&](size_t bytes) -> char* {
    char* p = ws + off;
    off += (bytes + 255) & ~(size_t)255;
    return p;
  };
  U16*  xp    = (U16*)take((size_t)32768 * 3072 * 2);   // 201.3 MB
  U16*  hcat  = (U16*)take((size_t)32768 * 768 * 2);    // 50.3 MB (doubles as x_bf16)
  U16*  wcat  = (U16*)take((size_t)3072 * 768 * 2);
  U16*  lwb   = (U16*)take((size_t)NL * 768 * 2);
  float* bcat = (float*)take(3072 * 4);
  int*  lens  = (int*)take(256);
  U64*  hx    = (U64*)take((size_t)2 * 8 * 3072 * 8);   // 384 KB tagged exchange
  float* em   = (float*)take((size_t)32768 * NL * 4);
  float* score= (float*)take(256);
  U16*  xbf   = hcat;   // alias: x_bf16 lives here until GEMM done, then region becomes h_cat

  (void)hipMemsetAsync(hx, 0, (size_t)2 * 8 * 3072 * 8, stream);  // clear tags (replay safety)
  k_pre<<<3136, 256, 0, stream>>>(x, (U64*)xbf, (const U32*)mask, lens,
                                  w_ih_f, w_ih_b, lin_w, b_f, b_b, wcat, lwb, bcat);
  k_gemm<<<1536, 512, 0, stream>>>(xbf, wcat, bcat, xp);
  k_rec<<<48, 256, 0, stream>>>(xp, w_hh_f, w_hh_b, lens, hcat, hx);
  k_em<<<1024, 256, 0, stream>>>(hcat, lwb, lin_b, em);
  k_crf<<<64, 64, 0, stream>>>(em, labels, lens, trans, startt, endt, score);
  k_final<<<1, 64, 0, stream>>>(score, out);
}